// Round 3
// baseline (260.178 us; speedup 1.0000x reference)
//
#include <hip/hip_runtime.h>
#include <math.h>

#define BB 32
#define CC 256
#define HH 64
#define WW 64
#define HWSZ (HH * WW)   // 4096
#define NCHUNK 16        // hw chunks per image (256 positions each)

typedef float f32x4 __attribute__((ext_vector_type(4)));

// ---------------------------------------------------------------------------
// Kernel 1: one pass over x. Grid: 32 b x 16 hw-chunks = 512 blocks, 256 thr.
// Wave w owns channels [64w, 64w+64) over the chunk's 256 positions
// (lane l -> float4 at hw0+4l).
//
// Per-channel sums via same-wave LDS transpose instead of 384 ds_swizzle
// butterflies/wave: per g, each lane writes its 16 channel-partials as
// 4x ds_write_b128 into cs[wave][lane][ch] (row stride 68 floats: 16B-aligned,
// bank-floor); after the g-loop each lane scalar-reads its channel's 64 lane
// partials (stride-68 -> 2-way bank, free) and stores chan_part coalesced.
// Channel sums are wave-local => no barrier needed for them; DS ops/wave
// drop 384 -> ~80. Pool max/sum merged across the 4 waves via LDS once.
// ---------------------------------------------------------------------------
__global__ __launch_bounds__(256, 2) void stats_kernel(
    const float* __restrict__ x, float* __restrict__ chan_part,
    float* __restrict__ pool_max, float* __restrict__ pool_sum) {
  const int b = blockIdx.x >> 4;
  const int chunk = blockIdx.x & 15;
  const int hw0 = chunk << 8;
  const int tid = threadIdx.x;
  const int wave = tid >> 6;
  const int lane = tid & 63;
  const int c_base = wave << 6;

  __shared__ float cs[4][64][68];   // [wave][lane][chan-in-wave], pad to 68
  __shared__ float4 lmax[4][64];
  __shared__ float4 lsum[4][64];

  const float4* xp =
      (const float4*)(x + ((size_t)b << 20) + ((size_t)c_base << 12) + hw0) + lane;

  float4 mx = make_float4(-3.4e38f, -3.4e38f, -3.4e38f, -3.4e38f);
  float4 sm = make_float4(0.f, 0.f, 0.f, 0.f);

  for (int g = 0; g < 4; ++g) {
    float s[16];
#pragma unroll
    for (int ci = 0; ci < 16; ++ci) {
      const float4 v = xp[(g * 16 + ci) * (HWSZ / 4)];
      mx.x = fmaxf(mx.x, v.x); mx.y = fmaxf(mx.y, v.y);
      mx.z = fmaxf(mx.z, v.z); mx.w = fmaxf(mx.w, v.w);
      sm.x += v.x; sm.y += v.y; sm.z += v.z; sm.w += v.w;
      s[ci] = (v.x + v.y) + (v.z + v.w);
    }
    // row offset lane*68 floats = 272B (16B-aligned); col g*16 -> aligned.
    float4* dst = (float4*)&cs[wave][lane][g * 16];
    dst[0] = make_float4(s[0],  s[1],  s[2],  s[3]);
    dst[1] = make_float4(s[4],  s[5],  s[6],  s[7]);
    dst[2] = make_float4(s[8],  s[9],  s[10], s[11]);
    dst[3] = make_float4(s[12], s[13], s[14], s[15]);
  }

  // Pool partials into LDS (cross-wave merge after barrier).
  lmax[wave][lane] = mx;
  lsum[wave][lane] = sm;

  // Wave-local channel reduce (same-wave DS ordering: no barrier needed).
  {
    float t0 = 0.f, t1 = 0.f, t2 = 0.f, t3 = 0.f;
#pragma unroll
    for (int j = 0; j < 64; j += 4) {
      t0 += cs[wave][j + 0][lane];
      t1 += cs[wave][j + 1][lane];
      t2 += cs[wave][j + 2][lane];
      t3 += cs[wave][j + 3][lane];
    }
    chan_part[((size_t)(b * NCHUNK + chunk)) * CC + c_base + lane] =
        (t0 + t1) + (t2 + t3);
  }

  __syncthreads();
  if (tid < 64) {
    const float4 a = lmax[0][tid], b4 = lmax[1][tid];
    const float4 c4 = lmax[2][tid], d4 = lmax[3][tid];
    float4 M;
    M.x = fmaxf(fmaxf(a.x, b4.x), fmaxf(c4.x, d4.x));
    M.y = fmaxf(fmaxf(a.y, b4.y), fmaxf(c4.y, d4.y));
    M.z = fmaxf(fmaxf(a.z, b4.z), fmaxf(c4.z, d4.z));
    M.w = fmaxf(fmaxf(a.w, b4.w), fmaxf(c4.w, d4.w));
    const float4 sa = lsum[0][tid], sb = lsum[1][tid];
    const float4 sc = lsum[2][tid], sd = lsum[3][tid];
    float4 S;
    S.x = (sa.x + sb.x) + (sc.x + sd.x);
    S.y = (sa.y + sb.y) + (sc.y + sd.y);
    S.z = (sa.z + sb.z) + (sc.z + sd.z);
    S.w = (sa.w + sb.w) + (sc.w + sd.w);
    ((float4*)(pool_max + ((size_t)b << 12) + hw0))[tid] = M;
    ((float4*)(pool_sum + ((size_t)b << 12) + hw0))[tid] = S;
  }
}

// ---------------------------------------------------------------------------
// Kernel 2 (fused): blocks [0,32) = ECA (fold chunk partials, conv1d k=5,
// sigmoid); blocks [32,544) = spatial 7x7 conv + sigmoid. Independent work,
// one dispatch.
// ---------------------------------------------------------------------------
__global__ __launch_bounds__(256) void attn_kernel(
    const float* __restrict__ chan_part, const float* __restrict__ w5,
    float* __restrict__ ch_w,
    const float* __restrict__ pool_max, const float* __restrict__ pool_sum,
    const float* __restrict__ w2, const float* __restrict__ bias,
    float* __restrict__ sp) {
  if (blockIdx.x < BB) {
    __shared__ float m[CC];
    const int b = blockIdx.x;
    const int c = threadIdx.x;
    float s = 0.0f;
#pragma unroll
    for (int k = 0; k < NCHUNK; ++k)
      s += chan_part[(size_t)(b * NCHUNK + k) * CC + c];
    m[c] = s * (1.0f / HWSZ);
    __syncthreads();

    float acc = 0.0f;
#pragma unroll
    for (int k = 0; k < 5; ++k) {
      int cc = c + k - 2;
      float v = (cc >= 0 && cc < CC) ? m[cc] : 0.0f;
      acc = fmaf(v, w5[k], acc);
    }
    ch_w[b * CC + c] = 1.0f / (1.0f + __expf(-acc));
  } else {
    const int idx = (blockIdx.x - BB) * 256 + threadIdx.x;  // over B*HW
    const int b = idx >> 12;
    const int hw = idx & (HWSZ - 1);
    const int h = hw >> 6;
    const int w = hw & 63;

    float acc = bias[0];
#pragma unroll
    for (int kh = 0; kh < 7; ++kh) {
      const int hh = h + kh - 3;
      if (hh < 0 || hh >= HH) continue;
#pragma unroll
      for (int kw = 0; kw < 7; ++kw) {
        const int ww = w + kw - 3;
        if (ww < 0 || ww >= WW) continue;
        const int off = b * HWSZ + hh * WW + ww;
        acc = fmaf(pool_max[off], w2[kh * 7 + kw], acc);
        acc = fmaf(pool_sum[off], w2[49 + kh * 7 + kw] * (1.0f / CC), acc);
      }
    }
    sp[idx] = 1.0f / (1.0f + __expf(-acc));
  }
}

// ---------------------------------------------------------------------------
// Kernel 3: out = x * (ch_w[b,c] + sp[b,hw] + 1).
// Block-uniform (b,c) -> ch_w is a scalar load. Nontemporal stores keep
// `out` from evicting x (128 MiB) out of the 256 MiB L3, so the x read
// here hits L3 (stats populated it). Store goes through a clang
// ext_vector_type(4) float — __builtin_nontemporal_store rejects HIP's
// struct-wrapped float4.
// ---------------------------------------------------------------------------
__global__ __launch_bounds__(256) void combine_kernel(
    const float* __restrict__ x, const float* __restrict__ ch_w,
    const float* __restrict__ sp, float* __restrict__ out) {
  const int blk = blockIdx.x;            // 2048 blocks; 1024 elems each
  const int b = blk >> 10;               // (blk*1024) >> 20
  const int c = (blk >> 2) & 255;
  const int hw0 = (blk & 3) << 10;
  const int t4 = threadIdx.x;            // float4 index within span

  const float cw = 1.0f + ch_w[b * CC + c];   // uniform -> scalar path
  const size_t plane = ((size_t)b << 20) + ((size_t)c << 12) + hw0;
  const float4 x4 = ((const float4*)(x + plane))[t4];
  const float4 s4 = ((const float4*)(sp + ((size_t)b << 12) + hw0))[t4];

  f32x4 o;
  o.x = x4.x * (cw + s4.x);
  o.y = x4.y * (cw + s4.y);
  o.z = x4.z * (cw + s4.z);
  o.w = x4.w * (cw + s4.w);
  __builtin_nontemporal_store(o, (f32x4*)(out + plane) + t4);
}

extern "C" void kernel_launch(void* const* d_in, const int* in_sizes, int n_in,
                              void* d_out, int out_size, void* d_ws, size_t ws_size,
                              hipStream_t stream) {
  const float* x    = (const float*)d_in[0];  // (32,256,64,64)
  const float* w1   = (const float*)d_in[1];  // (1,1,5)
  const float* w2   = (const float*)d_in[2];  // (1,2,7,7)
  const float* bias = (const float*)d_in[3];  // (1,)
  float* out = (float*)d_out;

  float* ws = (float*)d_ws;
  float* chan_part = ws;                       // 32*16*256 = 131072 floats
  float* ch_w      = ws + 131072;              // 8192
  float* pool_max  = ws + 139264;              // 131072
  float* pool_sum  = ws + 270336;              // 131072
  float* sp        = ws + 401408;              // 131072
  // Every workspace word is fully written before it is read -> no memsets,
  // no atomics, no init-pattern dependence.

  stats_kernel<<<BB * NCHUNK, 256, 0, stream>>>(x, chan_part, pool_max, pool_sum);
  attn_kernel<<<BB + (BB * HWSZ) / 256, 256, 0, stream>>>(
      chan_part, w1, ch_w, pool_max, pool_sum, w2, bias, sp);
  combine_kernel<<<(BB * CC * HWSZ) / (4 * 256), 256, 0, stream>>>(x, ch_w, sp, out);
}